// Round 1
// baseline (639.782 us; speedup 1.0000x reference)
//
#include <hip/hip_runtime.h>
#include <math.h>

// ---------------------------------------------------------------------------
// Problem: B=4, L=4096, D=P=256, tau=0.5
// out = (1/8) * sum_{b,l} [ log(S1-e^2) + log(S2-e^2) - 4*d[b,l] ]
//   S[b,q] = sum_{m<2L} exp(2 * Zhat[b,q]·Zhat[b,m]),  Zhat = [z1n; z2n]
//   d[b,l] = z1n[b,l]·z2n[b,l]
// ---------------------------------------------------------------------------

typedef __attribute__((ext_vector_type(8))) short short8;
typedef __attribute__((ext_vector_type(4))) short short4v;
typedef __attribute__((ext_vector_type(4))) float float4v;

__device__ __forceinline__ short f2bf(float f) {
    unsigned u = __builtin_bit_cast(unsigned, f);
    u += 0x7fffu + ((u >> 16) & 1u);          // RNE
    return (short)(u >> 16);
}
__device__ __forceinline__ float bf2f(short s) {
    unsigned u = ((unsigned)(unsigned short)s) << 16;
    return __builtin_bit_cast(float, u);
}

__device__ __forceinline__ void gl_lds16(const short* g, short* l) {
    __builtin_amdgcn_global_load_lds(
        (const __attribute__((address_space(1))) void*)g,
        (__attribute__((address_space(3))) void*)l, 16, 0, 0);
}

// ---------------------------------------------------------------------------
// Core: C[128x128] = A[arow0..+128, 0..256) * B[brow0..+128, 0..256)^T
// Both operands row-major [rows][256] bf16 (NT gemm).  256 threads = 4 waves,
// wave grid 2x2, each wave 64x64 via 4x4 frags of 16x16x32 bf16 MFMA.
// LDS: fragment-contiguous [kc][row][8] layout (matches global_load_lds's
// wave-uniform-base + lane*16 constraint; conflict-free ds_read_b128).
// ---------------------------------------------------------------------------
__device__ __forceinline__ void gemm_bt_core(
    const short* __restrict__ A, const short* __restrict__ B,
    int arow0, int brow0, short* lsA, short* lsB, float4v acc[4][4])
{
    const int tid  = threadIdx.x;
    const int w    = tid >> 6;
    const int lane = tid & 63;
    const int wm   = w & 1;
    const int wn   = w >> 1;

    for (int kt = 0; kt < 4; ++kt) {            // K=256 in 4 tiles of BK=64
        const int kbase = kt * 64;
#pragma unroll
        for (int r = 0; r < 4; ++r) {
            const int n   = (w * 4 + r) * 64 + lane;   // 16B slot index 0..1023
            const int kc  = n >> 7;                    // 0..7
            const int row = n & 127;
            const short* ga = A + (size_t)(arow0 + row) * 256 + kbase + kc * 8;
            const short* gb = B + (size_t)(brow0 + row) * 256 + kbase + kc * 8;
            gl_lds16(ga, lsA + (size_t)(w * 4 + r) * 512);  // base wave-uniform
            gl_lds16(gb, lsB + (size_t)(w * 4 + r) * 512);
        }
        __syncthreads();
#pragma unroll
        for (int ks = 0; ks < 2; ++ks) {
            const int kc = ks * 4 + (lane >> 4);
            short8 af[4], bfv[4];
#pragma unroll
            for (int mi = 0; mi < 4; ++mi)
                af[mi] = *(const short8*)(lsA + ((size_t)kc * 128 + wm * 64 + mi * 16 + (lane & 15)) * 8);
#pragma unroll
            for (int ni = 0; ni < 4; ++ni)
                bfv[ni] = *(const short8*)(lsB + ((size_t)kc * 128 + wn * 64 + ni * 16 + (lane & 15)) * 8);
#pragma unroll
            for (int mi = 0; mi < 4; ++mi)
#pragma unroll
                for (int ni = 0; ni < 4; ++ni)
                    acc[mi][ni] = __builtin_amdgcn_mfma_f32_16x16x32_bf16(
                        af[mi], bfv[ni], acc[mi][ni], 0, 0, 0);
        }
        __syncthreads();
    }
}

// ---------------------------------------------------------------------------
// fp32 -> bf16 conversion (vectorized, 4 elems/thread)
// ---------------------------------------------------------------------------
__global__ __launch_bounds__(256) void conv_kernel(
    const float* __restrict__ src, short* __restrict__ dst, int n4)
{
    int i = blockIdx.x * 256 + threadIdx.x;
    if (i < n4) {
        float4v v = ((const float4v*)src)[i];
        short4v o;
        o.x = f2bf(v.x); o.y = f2bf(v.y); o.z = f2bf(v.z); o.w = f2bf(v.w);
        ((short4v*)dst)[i] = o;
    }
}

// ---------------------------------------------------------------------------
// Projection GEMMs.  ELU=true : H = elu(A*W^T + bias) stored bf16
//                    ELU=false: Z = A*W^T + bias stored fp32
// grid (128, 2): 16384 x 256 output.
// C/D layout (verified m89/m91): col = lane&15, row = (lane>>4)*4 + reg.
// ---------------------------------------------------------------------------
template <bool ELU>
__global__ __launch_bounds__(256) void proj_kernel(
    const short* __restrict__ Abf, const short* __restrict__ Wbf,
    const float* __restrict__ bias, void* __restrict__ outp)
{
    __shared__ short lsA[8192];
    __shared__ short lsB[8192];
    const int arow0 = blockIdx.x * 128;
    const int brow0 = blockIdx.y * 128;
    float4v acc[4][4];
#pragma unroll
    for (int mi = 0; mi < 4; ++mi)
#pragma unroll
        for (int ni = 0; ni < 4; ++ni)
            acc[mi][ni] = (float4v){0.f, 0.f, 0.f, 0.f};

    gemm_bt_core(Abf, Wbf, arow0, brow0, lsA, lsB, acc);

    const int tid  = threadIdx.x;
    const int w    = tid >> 6;
    const int lane = tid & 63;
    const int wm   = w & 1;
    const int wn   = w >> 1;
    const int rowbase = arow0 + wm * 64 + (lane >> 4) * 4;
    const int colbase = brow0 + wn * 64 + (lane & 15);

#pragma unroll
    for (int ni = 0; ni < 4; ++ni) {
        const int col = colbase + ni * 16;
        const float bv = bias[col];
#pragma unroll
        for (int mi = 0; mi < 4; ++mi)
#pragma unroll
            for (int reg = 0; reg < 4; ++reg) {
                const int row = rowbase + mi * 16 + reg;
                float v = acc[mi][ni][reg] + bv;
                if (ELU) {
                    v = (v > 0.f) ? v : expm1f(v);
                    ((short*)outp)[(size_t)row * 256 + col] = f2bf(v);
                } else {
                    ((float*)outp)[(size_t)row * 256 + col] = v;
                }
            }
    }
}

// ---------------------------------------------------------------------------
// Row-normalize Z (fp32 [16384][256]) -> bf16 zn[b][set][l][256]
// One wave per row.
// ---------------------------------------------------------------------------
__global__ __launch_bounds__(256) void norm_kernel(
    const float* __restrict__ Z, short* __restrict__ zn, int set)
{
    const int tid  = threadIdx.x;
    const int w    = tid >> 6;
    const int lane = tid & 63;
    const int row  = blockIdx.x * 4 + w;
    const float4v* zr = (const float4v*)(Z + (size_t)row * 256);
    float4v v = zr[lane];
    float ss = v.x * v.x + v.y * v.y + v.z * v.z + v.w * v.w;
    ss += __shfl_xor(ss, 1);  ss += __shfl_xor(ss, 2);  ss += __shfl_xor(ss, 4);
    ss += __shfl_xor(ss, 8);  ss += __shfl_xor(ss, 16); ss += __shfl_xor(ss, 32);
    const float inv = 1.0f / fmaxf(sqrtf(ss), 1e-12f);
    const int b = row >> 12;
    const int l = row & 4095;
    short4v o;
    o.x = f2bf(v.x * inv); o.y = f2bf(v.y * inv);
    o.z = f2bf(v.z * inv); o.w = f2bf(v.w * inv);
    short4v* dst = (short4v*)(zn + ((size_t)(b * 2 + set) * 4096 + l) * 256);
    dst[lane] = o;
}

// ---------------------------------------------------------------------------
// Gram kernel: per batch b, S[b,q] += rowsum(exp(2 * Zhat[q]·Zhat[m]))
// over this block's 128x128 tile.  grid (64, 64, 4).
// ---------------------------------------------------------------------------
__global__ __launch_bounds__(256) void gram_kernel(
    const short* __restrict__ zn, float* __restrict__ S)
{
    __shared__ short lsA[8192];
    __shared__ short lsB[8192];
    const int b = blockIdx.z;
    const short* Z = zn + (size_t)b * (8192 * 256);
    const int arow0 = blockIdx.x * 128;
    const int brow0 = blockIdx.y * 128;
    float4v acc[4][4];
#pragma unroll
    for (int mi = 0; mi < 4; ++mi)
#pragma unroll
        for (int ni = 0; ni < 4; ++ni)
            acc[mi][ni] = (float4v){0.f, 0.f, 0.f, 0.f};

    gemm_bt_core(Z, Z, arow0, brow0, lsA, lsB, acc);

    const int tid  = threadIdx.x;
    const int w    = tid >> 6;
    const int lane = tid & 63;
    const int wm   = w & 1;

    // exp and per-lane partial rowsum over this wave's 64 columns
    float p[4][4];
#pragma unroll
    for (int mi = 0; mi < 4; ++mi)
#pragma unroll
        for (int reg = 0; reg < 4; ++reg) {
            float s = 0.f;
#pragma unroll
            for (int ni = 0; ni < 4; ++ni)
                s += __expf(2.0f * acc[mi][ni][reg]);
            p[mi][reg] = s;
        }
    // reduce across the 16 lanes sharing a row group (cols)
#pragma unroll
    for (int mi = 0; mi < 4; ++mi)
#pragma unroll
        for (int reg = 0; reg < 4; ++reg) {
            float v = p[mi][reg];
            v += __shfl_xor(v, 1); v += __shfl_xor(v, 2);
            v += __shfl_xor(v, 4); v += __shfl_xor(v, 8);
            p[mi][reg] = v;
        }
    if ((lane & 15) == 0) {
        const int g = lane >> 4;
        float* Sb = S + (size_t)b * 8192 + arow0 + wm * 64;
#pragma unroll
        for (int mi = 0; mi < 4; ++mi)
#pragma unroll
            for (int reg = 0; reg < 4; ++reg)
                atomicAdd(&Sb[mi * 16 + g * 4 + reg], p[mi][reg]);
    }
}

// ---------------------------------------------------------------------------
// Final: one wave per (b,l): d = z1n·z2n; t = log(S1-e2)+log(S2-e2)-4d
// out += 0.125 * t
// ---------------------------------------------------------------------------
__global__ __launch_bounds__(256) void final_kernel(
    const short* __restrict__ zn, const float* __restrict__ S,
    float* __restrict__ out)
{
    const int tid  = threadIdx.x;
    const int w    = tid >> 6;
    const int lane = tid & 63;
    const int idx  = blockIdx.x * 4 + w;
    const int b = idx >> 12;
    const int l = idx & 4095;
    const short4v* z1 = (const short4v*)(zn + ((size_t)(b * 2 + 0) * 4096 + l) * 256);
    const short4v* z2 = (const short4v*)(zn + ((size_t)(b * 2 + 1) * 4096 + l) * 256);
    short4v a = z1[lane];
    short4v c = z2[lane];
    float d = bf2f(a.x) * bf2f(c.x) + bf2f(a.y) * bf2f(c.y)
            + bf2f(a.z) * bf2f(c.z) + bf2f(a.w) * bf2f(c.w);
    d += __shfl_xor(d, 1);  d += __shfl_xor(d, 2);  d += __shfl_xor(d, 4);
    d += __shfl_xor(d, 8);  d += __shfl_xor(d, 16); d += __shfl_xor(d, 32);
    if (lane == 0) {
        const float E2 = 7.3890560989306495f;   // exp(1/tau)
        float s1 = S[(size_t)b * 8192 + l];
        float s2 = S[(size_t)b * 8192 + 4096 + l];
        float t = logf(s1 - E2) + logf(s2 - E2) - 4.0f * d;
        atomicAdd(out, 0.125f * t);
    }
}

// ---------------------------------------------------------------------------
// Workspace layout (bytes):
//   [0,        131072)  S        : 4*8192 fp32
//   [131072,   262144)  W1bf     : 256*256 bf16
//   [262144,   393216)  W2bf     : 256*256 bf16
//   [393216, 17170432)  zn       : 4*2*4096*256 bf16
//   [17170432,25559040) Hbf      : 16384*256 bf16
//   [25559040,42336256) Xbf/Zf32 : aliased (Xbf dead once Z is written)
// total ~40.4 MB
// ---------------------------------------------------------------------------
extern "C" void kernel_launch(void* const* d_in, const int* in_sizes, int n_in,
                              void* d_out, int out_size, void* d_ws, size_t ws_size,
                              hipStream_t stream)
{
    const float* X1 = (const float*)d_in[0];
    const float* X2 = (const float*)d_in[1];
    const float* W1 = (const float*)d_in[2];
    const float* b1 = (const float*)d_in[3];
    const float* W2 = (const float*)d_in[4];
    const float* b2 = (const float*)d_in[5];

    char* ws = (char*)d_ws;
    float* S    = (float*)(ws + 0);
    short* W1bf = (short*)(ws + 131072);
    short* W2bf = (short*)(ws + 262144);
    short* zn   = (short*)(ws + 393216);
    short* Hbf  = (short*)(ws + 17170432);
    short* Xbf  = (short*)(ws + 25559040);
    float* Zf   = (float*)(ws + 25559040);

    hipMemsetAsync(S, 0, 131072, stream);
    hipMemsetAsync(d_out, 0, sizeof(float), stream);

    conv_kernel<<<64, 256, 0, stream>>>(W1, W1bf, 16384);
    conv_kernel<<<64, 256, 0, stream>>>(W2, W2bf, 16384);

    for (int s = 0; s < 2; ++s) {
        const float* X = s ? X2 : X1;
        conv_kernel<<<4096, 256, 0, stream>>>(X, Xbf, 1048576);
        proj_kernel<true ><<<dim3(128, 2), 256, 0, stream>>>(Xbf, W1bf, b1, (void*)Hbf);
        proj_kernel<false><<<dim3(128, 2), 256, 0, stream>>>(Hbf, W2bf, b2, (void*)Zf);
        norm_kernel<<<4096, 256, 0, stream>>>(Zf, zn, s);
    }

    gram_kernel<<<dim3(64, 64, 4), 256, 0, stream>>>(zn, S);
    final_kernel<<<4096, 256, 0, stream>>>(zn, S, (float*)d_out);
}

// Round 2
// 418.690 us; speedup vs baseline: 1.5281x; 1.5281x over previous
//
#include <hip/hip_runtime.h>
#include <math.h>

// ---------------------------------------------------------------------------
// Problem: B=4, L=4096, D=P=256, tau=0.5
// out = (1/8) * sum_{b,l} [ log(S1-e^2) + log(S2-e^2) - 4*d[b,l] ]
//   S[b,q] = sum_{m<2L} exp(2 * Zhat[b,q]·Zhat[b,m]),  Zhat = [z1n; z2n]
//   d[b,l] = z1n[b,l]·z2n[b,l]
// E = exp(2*Zhat Zhat^T) is SYMMETRIC: compute only upper-triangular tiles;
// off-diag tile (i,j) contributes rowsums to S[i-block] and colsums to
// S[j-block].  1.97x less MFMA than the full Gram.
// ---------------------------------------------------------------------------

typedef __attribute__((ext_vector_type(8))) short short8;
typedef __attribute__((ext_vector_type(4))) short short4v;
typedef __attribute__((ext_vector_type(4))) float float4v;

__device__ __forceinline__ short f2bf(float f) {
    unsigned u = __builtin_bit_cast(unsigned, f);
    u += 0x7fffu + ((u >> 16) & 1u);          // RNE
    return (short)(u >> 16);
}
__device__ __forceinline__ float bf2f(short s) {
    unsigned u = ((unsigned)(unsigned short)s) << 16;
    return __builtin_bit_cast(float, u);
}

__device__ __forceinline__ void gl_lds16(const short* g, short* l) {
    __builtin_amdgcn_global_load_lds(
        (const __attribute__((address_space(1))) void*)g,
        (__attribute__((address_space(3))) void*)l, 16, 0, 0);
}

// ---------------------------------------------------------------------------
// Core: C[128x128] = A[arow0..+128, 0..256) * B[brow0..+128, 0..256)^T
// Both operands row-major [rows][256] bf16 (NT gemm).  256 threads = 4 waves,
// wave grid 2x2, each wave 64x64 via 4x4 frags of 16x16x32 bf16 MFMA.
// LDS: fragment-contiguous [kc][row][8] layout (matches global_load_lds's
// wave-uniform-base + lane*16 constraint; conflict-free ds_read_b128).
// ---------------------------------------------------------------------------
__device__ __forceinline__ void gemm_bt_core(
    const short* __restrict__ A, const short* __restrict__ B,
    int arow0, int brow0, short* lsA, short* lsB, float4v acc[4][4])
{
    const int tid  = threadIdx.x;
    const int w    = tid >> 6;
    const int lane = tid & 63;
    const int wm   = w & 1;
    const int wn   = w >> 1;

    for (int kt = 0; kt < 4; ++kt) {            // K=256 in 4 tiles of BK=64
        const int kbase = kt * 64;
#pragma unroll
        for (int r = 0; r < 4; ++r) {
            const int n   = (w * 4 + r) * 64 + lane;   // 16B slot index 0..1023
            const int kc  = n >> 7;                    // 0..7
            const int row = n & 127;
            const short* ga = A + (size_t)(arow0 + row) * 256 + kbase + kc * 8;
            const short* gb = B + (size_t)(brow0 + row) * 256 + kbase + kc * 8;
            gl_lds16(ga, lsA + (size_t)(w * 4 + r) * 512);  // base wave-uniform
            gl_lds16(gb, lsB + (size_t)(w * 4 + r) * 512);
        }
        __syncthreads();
#pragma unroll
        for (int ks = 0; ks < 2; ++ks) {
            const int kc = ks * 4 + (lane >> 4);
            short8 af[4], bfv[4];
#pragma unroll
            for (int mi = 0; mi < 4; ++mi)
                af[mi] = *(const short8*)(lsA + ((size_t)kc * 128 + wm * 64 + mi * 16 + (lane & 15)) * 8);
#pragma unroll
            for (int ni = 0; ni < 4; ++ni)
                bfv[ni] = *(const short8*)(lsB + ((size_t)kc * 128 + wn * 64 + ni * 16 + (lane & 15)) * 8);
#pragma unroll
            for (int mi = 0; mi < 4; ++mi)
#pragma unroll
                for (int ni = 0; ni < 4; ++ni)
                    acc[mi][ni] = __builtin_amdgcn_mfma_f32_16x16x32_bf16(
                        af[mi], bfv[ni], acc[mi][ni], 0, 0, 0);
        }
        __syncthreads();
    }
}

// ---------------------------------------------------------------------------
// fp32 -> bf16 conversion (vectorized, 4 elems/thread)
// ---------------------------------------------------------------------------
__global__ __launch_bounds__(256) void conv_kernel(
    const float* __restrict__ src, short* __restrict__ dst, int n4)
{
    int i = blockIdx.x * 256 + threadIdx.x;
    if (i < n4) {
        float4v v = ((const float4v*)src)[i];
        short4v o;
        o.x = f2bf(v.x); o.y = f2bf(v.y); o.z = f2bf(v.z); o.w = f2bf(v.w);
        ((short4v*)dst)[i] = o;
    }
}

// ---------------------------------------------------------------------------
// Projection GEMMs.  ELU=true : H = elu(A*W^T + bias) stored bf16
//                    ELU=false: Z = A*W^T + bias stored fp32
// grid (128, 2): 16384 x 256 output.
// C/D layout (verified m89/m91): col = lane&15, row = (lane>>4)*4 + reg.
// ---------------------------------------------------------------------------
template <bool ELU>
__global__ __launch_bounds__(256) void proj_kernel(
    const short* __restrict__ Abf, const short* __restrict__ Wbf,
    const float* __restrict__ bias, void* __restrict__ outp)
{
    __shared__ short lsA[8192];
    __shared__ short lsB[8192];
    const int arow0 = blockIdx.x * 128;
    const int brow0 = blockIdx.y * 128;
    float4v acc[4][4];
#pragma unroll
    for (int mi = 0; mi < 4; ++mi)
#pragma unroll
        for (int ni = 0; ni < 4; ++ni)
            acc[mi][ni] = (float4v){0.f, 0.f, 0.f, 0.f};

    gemm_bt_core(Abf, Wbf, arow0, brow0, lsA, lsB, acc);

    const int tid  = threadIdx.x;
    const int w    = tid >> 6;
    const int lane = tid & 63;
    const int wm   = w & 1;
    const int wn   = w >> 1;
    const int rowbase = arow0 + wm * 64 + (lane >> 4) * 4;
    const int colbase = brow0 + wn * 64 + (lane & 15);

#pragma unroll
    for (int ni = 0; ni < 4; ++ni) {
        const int col = colbase + ni * 16;
        const float bv = bias[col];
#pragma unroll
        for (int mi = 0; mi < 4; ++mi)
#pragma unroll
            for (int reg = 0; reg < 4; ++reg) {
                const int row = rowbase + mi * 16 + reg;
                float v = acc[mi][ni][reg] + bv;
                if (ELU) {
                    v = (v > 0.f) ? v : expm1f(v);
                    ((short*)outp)[(size_t)row * 256 + col] = f2bf(v);
                } else {
                    ((float*)outp)[(size_t)row * 256 + col] = v;
                }
            }
    }
}

// ---------------------------------------------------------------------------
// Row-normalize Z (fp32 [16384][256]) -> bf16 zn[b][set][l][256]
// One wave per row.
// ---------------------------------------------------------------------------
__global__ __launch_bounds__(256) void norm_kernel(
    const float* __restrict__ Z, short* __restrict__ zn, int set)
{
    const int tid  = threadIdx.x;
    const int w    = tid >> 6;
    const int lane = tid & 63;
    const int row  = blockIdx.x * 4 + w;
    const float4v* zr = (const float4v*)(Z + (size_t)row * 256);
    float4v v = zr[lane];
    float ss = v.x * v.x + v.y * v.y + v.z * v.z + v.w * v.w;
    ss += __shfl_xor(ss, 1);  ss += __shfl_xor(ss, 2);  ss += __shfl_xor(ss, 4);
    ss += __shfl_xor(ss, 8);  ss += __shfl_xor(ss, 16); ss += __shfl_xor(ss, 32);
    const float inv = 1.0f / fmaxf(sqrtf(ss), 1e-12f);
    const int b = row >> 12;
    const int l = row & 4095;
    short4v o;
    o.x = f2bf(v.x * inv); o.y = f2bf(v.y * inv);
    o.z = f2bf(v.z * inv); o.w = f2bf(v.w * inv);
    short4v* dst = (short4v*)(zn + ((size_t)(b * 2 + set) * 4096 + l) * 256);
    dst[lane] = o;
}

// ---------------------------------------------------------------------------
// Symmetric Gram kernel.  grid (64, 64, 4); only blocks with j>=i do work.
// Off-diag tile: rowsums -> S[i-block], colsums -> S[j-block].
// Diag tile: rowsums only.
// Wave partials combined in LDS -> 128 row + 128 col atomics per block.
// ---------------------------------------------------------------------------
__global__ __launch_bounds__(256) void gram_kernel(
    const short* __restrict__ zn, float* __restrict__ S)
{
    const int bi = blockIdx.x;
    const int bj = blockIdx.y;
    if (bj < bi) return;                       // upper triangle only
    __shared__ short lsA[8192];
    __shared__ short lsB[8192];
    const int b = blockIdx.z;
    const short* Z = zn + (size_t)b * (8192 * 256);
    const int arow0 = bi * 128;
    const int brow0 = bj * 128;
    float4v acc[4][4];
#pragma unroll
    for (int mi = 0; mi < 4; ++mi)
#pragma unroll
        for (int ni = 0; ni < 4; ++ni)
            acc[mi][ni] = (float4v){0.f, 0.f, 0.f, 0.f};

    gemm_bt_core(Z, Z, arow0, brow0, lsA, lsB, acc);

    const int tid  = threadIdx.x;
    const int w    = tid >> 6;
    const int lane = tid & 63;
    const int wm   = w & 1;
    const int wn   = w >> 1;

    // exp once; accumulate row partials rs[mi][reg] and col partials cs[ni]
    float rs[4][4];
    float cs[4] = {0.f, 0.f, 0.f, 0.f};
#pragma unroll
    for (int mi = 0; mi < 4; ++mi)
#pragma unroll
        for (int reg = 0; reg < 4; ++reg) {
            float s = 0.f;
#pragma unroll
            for (int ni = 0; ni < 4; ++ni) {
                float e = __expf(2.0f * acc[mi][ni][reg]);
                s += e;
                cs[ni] += e;
            }
            rs[mi][reg] = s;
        }
    // row partials: reduce across the 16 lanes of each row group
#pragma unroll
    for (int mi = 0; mi < 4; ++mi)
#pragma unroll
        for (int reg = 0; reg < 4; ++reg) {
            float v = rs[mi][reg];
            v += __shfl_xor(v, 1); v += __shfl_xor(v, 2);
            v += __shfl_xor(v, 4); v += __shfl_xor(v, 8);
            rs[mi][reg] = v;
        }
    // col partials: reduce across the 4 row groups (lanes differing in bits 4,5)
#pragma unroll
    for (int ni = 0; ni < 4; ++ni) {
        float v = cs[ni];
        v += __shfl_xor(v, 16); v += __shfl_xor(v, 32);
        cs[ni] = v;
    }

    // combine wave partials in LDS (reuse lsA; gemm core ends with syncthreads)
    float* rowbuf = (float*)lsA;        // [2 (wn)][128]
    float* colbuf = rowbuf + 256;       // [2 (wm)][128]
    if ((lane & 15) == 0) {
        const int g = lane >> 4;
#pragma unroll
        for (int mi = 0; mi < 4; ++mi)
#pragma unroll
            for (int reg = 0; reg < 4; ++reg)
                rowbuf[wn * 128 + wm * 64 + mi * 16 + g * 4 + reg] = rs[mi][reg];
    }
    if (lane < 16) {
#pragma unroll
        for (int ni = 0; ni < 4; ++ni)
            colbuf[wm * 128 + wn * 64 + ni * 16 + lane] = cs[ni];
    }
    __syncthreads();

    float* Sb = S + (size_t)b * 8192;
    if (tid < 128) {
        float v = rowbuf[tid] + rowbuf[128 + tid];
        atomicAdd(&Sb[arow0 + tid], v);
    } else if (bi != bj) {
        const int c = tid - 128;
        float v = colbuf[c] + colbuf[128 + c];
        atomicAdd(&Sb[brow0 + c], v);
    }
}

// ---------------------------------------------------------------------------
// Final: grid-stride over 16384 rows, one wave per row-iteration.
// d = z1n.z2n; t = log(S1-e2)+log(S2-e2)-4d; block-reduce; 1 atomic/block.
// grid: 64 blocks x 256 threads (4 waves) -> 64 rows per wave.
// ---------------------------------------------------------------------------
__global__ __launch_bounds__(256) void final_kernel(
    const short* __restrict__ zn, const float* __restrict__ S,
    float* __restrict__ out)
{
    __shared__ float red[4];
    const int tid  = threadIdx.x;
    const int w    = tid >> 6;
    const int lane = tid & 63;
    const float E2 = 7.3890560989306495f;   // exp(1/tau)

    float tacc = 0.f;
    for (int idx = blockIdx.x * 4 + w; idx < 16384; idx += 256) {
        const int b = idx >> 12;
        const int l = idx & 4095;
        const short4v* z1 = (const short4v*)(zn + ((size_t)(b * 2 + 0) * 4096 + l) * 256);
        const short4v* z2 = (const short4v*)(zn + ((size_t)(b * 2 + 1) * 4096 + l) * 256);
        short4v a = z1[lane];
        short4v c = z2[lane];
        float d = bf2f(a.x) * bf2f(c.x) + bf2f(a.y) * bf2f(c.y)
                + bf2f(a.z) * bf2f(c.z) + bf2f(a.w) * bf2f(c.w);
        d += __shfl_xor(d, 1);  d += __shfl_xor(d, 2);  d += __shfl_xor(d, 4);
        d += __shfl_xor(d, 8);  d += __shfl_xor(d, 16); d += __shfl_xor(d, 32);
        if (lane == 0) {
            float s1 = S[(size_t)b * 8192 + l];
            float s2 = S[(size_t)b * 8192 + 4096 + l];
            tacc += logf(s1 - E2) + logf(s2 - E2) - 4.0f * d;
        }
    }
    if (lane == 0) red[w] = tacc;
    __syncthreads();
    if (tid == 0) {
        float t = red[0] + red[1] + red[2] + red[3];
        atomicAdd(out, 0.125f * t);
    }
}

// ---------------------------------------------------------------------------
// Workspace layout (bytes):
//   [0,        131072)  S        : 4*8192 fp32
//   [131072,   262144)  W1bf     : 256*256 bf16
//   [262144,   393216)  W2bf     : 256*256 bf16
//   [393216, 17170432)  zn       : 4*2*4096*256 bf16
//   [17170432,25559040) Hbf      : 16384*256 bf16
//   [25559040,42336256) Xbf/Zf32 : aliased (Xbf dead once Z is written)
// total ~40.4 MB
// ---------------------------------------------------------------------------
extern "C" void kernel_launch(void* const* d_in, const int* in_sizes, int n_in,
                              void* d_out, int out_size, void* d_ws, size_t ws_size,
                              hipStream_t stream)
{
    const float* X1 = (const float*)d_in[0];
    const float* X2 = (const float*)d_in[1];
    const float* W1 = (const float*)d_in[2];
    const float* b1 = (const float*)d_in[3];
    const float* W2 = (const float*)d_in[4];
    const float* b2 = (const float*)d_in[5];

    char* ws = (char*)d_ws;
    float* S    = (float*)(ws + 0);
    short* W1bf = (short*)(ws + 131072);
    short* W2bf = (short*)(ws + 262144);
    short* zn   = (short*)(ws + 393216);
    short* Hbf  = (short*)(ws + 17170432);
    short* Xbf  = (short*)(ws + 25559040);
    float* Zf   = (float*)(ws + 25559040);

    hipMemsetAsync(S, 0, 131072, stream);
    hipMemsetAsync(d_out, 0, sizeof(float), stream);

    conv_kernel<<<64, 256, 0, stream>>>(W1, W1bf, 16384);
    conv_kernel<<<64, 256, 0, stream>>>(W2, W2bf, 16384);

    for (int s = 0; s < 2; ++s) {
        const float* X = s ? X2 : X1;
        conv_kernel<<<4096, 256, 0, stream>>>(X, Xbf, 1048576);
        proj_kernel<true ><<<dim3(128, 2), 256, 0, stream>>>(Xbf, W1bf, b1, (void*)Hbf);
        proj_kernel<false><<<dim3(128, 2), 256, 0, stream>>>(Hbf, W2bf, b2, (void*)Zf);
        norm_kernel<<<4096, 256, 0, stream>>>(Zf, zn, s);
    }

    gram_kernel<<<dim3(64, 64, 4), 256, 0, stream>>>(zn, S);
    final_kernel<<<64, 256, 0, stream>>>(zn, S, (float*)d_out);
}

// Round 3
// 343.856 us; speedup vs baseline: 1.8606x; 1.2176x over previous
//
#include <hip/hip_runtime.h>
#include <math.h>

// ---------------------------------------------------------------------------
// Problem: B=4, L=4096, D=P=256, tau=0.5
// out = (1/8) * sum_{b,l} [ log(S1-e^2) + log(S2-e^2) - 4*d[b,l] ]
//   S[b,q] = sum_{m<2L} exp(2 * Zhat[b,q]·Zhat[b,m]),  Zhat = [z1n; z2n]
// Symmetric Gram: 256-row super-tiles; diag super-tile full (rowsums only),
// off-diag 256x128 tiles contribute rowsums AND colsums.
// ---------------------------------------------------------------------------

typedef __attribute__((ext_vector_type(8))) short short8;
typedef __attribute__((ext_vector_type(4))) short short4v;
typedef __attribute__((ext_vector_type(4))) float float4v;

__device__ __forceinline__ short f2bf(float f) {
    unsigned u = __builtin_bit_cast(unsigned, f);
    u += 0x7fffu + ((u >> 16) & 1u);          // RNE
    return (short)(u >> 16);
}
__device__ __forceinline__ float bf2f(short s) {
    unsigned u = ((unsigned)(unsigned short)s) << 16;
    return __builtin_bit_cast(float, u);
}

__device__ __forceinline__ void gl_lds16(const short* g, short* l) {
    __builtin_amdgcn_global_load_lds(
        (const __attribute__((address_space(1))) void*)g,
        (__attribute__((address_space(3))) void*)l, 16, 0, 0);
}

// ---------------------------------------------------------------------------
// 512-thread NT-GEMM core: C[RA x RB] = A[arow0..+RA, 256) * B[brow0..+RB)^T
// 8 waves in grid NWM x (8/NWM); each wave 64x64 via 4x4 frags 16x16x32 bf16.
// LDS fragment-contiguous [kc][row][8] per operand; global_load_lds width 16
// (wave-uniform LDS base, chunk = 64 slots of 16B).
// ---------------------------------------------------------------------------
template <int RA, int RB, int NWM>
__device__ __forceinline__ void gemm512_core(
    const short* __restrict__ A, const short* __restrict__ B,
    int arow0, int brow0, short* lsA, short* lsB, float4v acc[4][4])
{
    const int tid  = threadIdx.x;
    const int w    = tid >> 6;
    const int lane = tid & 63;
    const int wm   = w % NWM;
    const int wn   = w / NWM;
    constexpr int ACH = RA / 8;               // A chunks of 64 slots

    for (int kt = 0; kt < 4; ++kt) {          // K=256 in 4 tiles of BK=64
        const int kbase = kt * 64;
#pragma unroll
        for (int r = 0; r < 6; ++r) {
            const int c = w * 6 + r;          // 0..47 chunks, wave-uniform
            if (c < ACH) {
                const int s   = c * 64 + lane;
                const int kc  = s / RA;
                const int row = s % RA;
                gl_lds16(A + (size_t)(arow0 + row) * 256 + kbase + kc * 8,
                         lsA + (size_t)c * 512);
            } else {
                const int s   = (c - ACH) * 64 + lane;
                const int kc  = s / RB;
                const int row = s % RB;
                gl_lds16(B + (size_t)(brow0 + row) * 256 + kbase + kc * 8,
                         lsB + (size_t)(c - ACH) * 512);
            }
        }
        __syncthreads();
#pragma unroll
        for (int ks = 0; ks < 2; ++ks) {
            const int kc = ks * 4 + (lane >> 4);
            short8 af[4], bfv[4];
#pragma unroll
            for (int mi = 0; mi < 4; ++mi)
                af[mi] = *(const short8*)(lsA + ((size_t)kc * RA + wm * 64 + mi * 16 + (lane & 15)) * 8);
#pragma unroll
            for (int ni = 0; ni < 4; ++ni)
                bfv[ni] = *(const short8*)(lsB + ((size_t)kc * RB + wn * 64 + ni * 16 + (lane & 15)) * 8);
#pragma unroll
            for (int mi = 0; mi < 4; ++mi)
#pragma unroll
                for (int ni = 0; ni < 4; ++ni)
                    acc[mi][ni] = __builtin_amdgcn_mfma_f32_16x16x32_bf16(
                        af[mi], bfv[ni], acc[mi][ni], 0, 0, 0);
        }
        __syncthreads();
    }
}

// ---------------------------------------------------------------------------
// fp32 -> bf16: both X inputs in one dispatch.  grid 8192 x 256.
// ---------------------------------------------------------------------------
__global__ __launch_bounds__(256) void convX_kernel(
    const float* __restrict__ X1, const float* __restrict__ X2,
    short* __restrict__ dst)
{
    int i = blockIdx.x * 256 + threadIdx.x;           // 0..2097151 (x4 elems)
    const float* src = (i < 1048576) ? X1 : X2;
    int j = i & 1048575;
    float4v v = ((const float4v*)src)[j];
    short4v o;
    o.x = f2bf(v.x); o.y = f2bf(v.y); o.z = f2bf(v.z); o.w = f2bf(v.w);
    ((short4v*)dst)[i] = o;
}

// Both weights in one dispatch. grid 128 x 256.
__global__ __launch_bounds__(256) void convW_kernel(
    const float* __restrict__ W1, const float* __restrict__ W2,
    short* __restrict__ d1, short* __restrict__ d2)
{
    int i = blockIdx.x * 256 + threadIdx.x;           // 0..32767
    const float* src = (i < 16384) ? W1 : W2;
    short* dst = (i < 16384) ? d1 : d2;
    int j = i & 16383;
    float4v v = ((const float4v*)src)[j];
    short4v o;
    o.x = f2bf(v.x); o.y = f2bf(v.y); o.z = f2bf(v.z); o.w = f2bf(v.w);
    ((short4v*)dst)[j] = o;
}

// ---------------------------------------------------------------------------
// proj1: H = elu(X*W1^T + b1) bf16.  M=32768 rows (both sets), tile 128x256,
// grid 256 x 512thr.
// ---------------------------------------------------------------------------
__global__ __launch_bounds__(512) void proj1_kernel(
    const short* __restrict__ Xbf, const short* __restrict__ W1bf,
    const float* __restrict__ b1, short* __restrict__ Hbf)
{
    __shared__ short lsA[8192];    // 128 x 64
    __shared__ short lsB[16384];   // 256 x 64
    const int arow0 = blockIdx.x * 128;
    float4v acc[4][4];
#pragma unroll
    for (int mi = 0; mi < 4; ++mi)
#pragma unroll
        for (int ni = 0; ni < 4; ++ni)
            acc[mi][ni] = (float4v){0.f, 0.f, 0.f, 0.f};

    gemm512_core<128, 256, 2>(Xbf, W1bf, arow0, 0, lsA, lsB, acc);

    const int tid  = threadIdx.x;
    const int w    = tid >> 6;
    const int lane = tid & 63;
    const int wm   = w % 2;
    const int wn   = w / 2;
    const int rowbase = arow0 + wm * 64 + (lane >> 4) * 4;
    const int colbase = wn * 64 + (lane & 15);
#pragma unroll
    for (int ni = 0; ni < 4; ++ni) {
        const int col = colbase + ni * 16;
        const float bv = b1[col];
#pragma unroll
        for (int mi = 0; mi < 4; ++mi)
#pragma unroll
            for (int reg = 0; reg < 4; ++reg) {
                const int row = rowbase + mi * 16 + reg;
                float v = acc[mi][ni][reg] + bv;
                v = (v > 0.f) ? v : expm1f(v);
                Hbf[(size_t)row * 256 + col] = f2bf(v);
            }
    }
}

// ---------------------------------------------------------------------------
// proj2 + row-normalize fused: Z = H*W2^T + b2; zn = Z/||Z|| bf16, written
// into [b][set][l][256] order.  grid 256 x 512thr.
// ---------------------------------------------------------------------------
__global__ __launch_bounds__(512) void proj2norm_kernel(
    const short* __restrict__ Hbf, const short* __restrict__ W2bf,
    const float* __restrict__ b2, short* __restrict__ zn)
{
    __shared__ short lsA[8192];
    __shared__ short lsB[16384];
    __shared__ float rssq[4][128];
    __shared__ float rinv[128];
    const int arow0 = blockIdx.x * 128;
    float4v acc[4][4];
#pragma unroll
    for (int mi = 0; mi < 4; ++mi)
#pragma unroll
        for (int ni = 0; ni < 4; ++ni)
            acc[mi][ni] = (float4v){0.f, 0.f, 0.f, 0.f};

    gemm512_core<128, 256, 2>(Hbf, W2bf, arow0, 0, lsA, lsB, acc);

    const int tid  = threadIdx.x;
    const int w    = tid >> 6;
    const int lane = tid & 63;
    const int wm   = w % 2;
    const int wn   = w / 2;

    // bias then per-row sum-of-squares partials (this wave's 64 cols)
#pragma unroll
    for (int ni = 0; ni < 4; ++ni) {
        const float bv = b2[wn * 64 + ni * 16 + (lane & 15)];
#pragma unroll
        for (int mi = 0; mi < 4; ++mi)
#pragma unroll
            for (int reg = 0; reg < 4; ++reg)
                acc[mi][ni][reg] += bv;
    }
    float ps[4][4];
#pragma unroll
    for (int mi = 0; mi < 4; ++mi)
#pragma unroll
        for (int reg = 0; reg < 4; ++reg) {
            float s = 0.f;
#pragma unroll
            for (int ni = 0; ni < 4; ++ni) {
                float v = acc[mi][ni][reg];
                s += v * v;
            }
            s += __shfl_xor(s, 1); s += __shfl_xor(s, 2);
            s += __shfl_xor(s, 4); s += __shfl_xor(s, 8);
            ps[mi][reg] = s;
        }
    if ((lane & 15) == 0) {
        const int g = lane >> 4;
#pragma unroll
        for (int mi = 0; mi < 4; ++mi)
#pragma unroll
            for (int reg = 0; reg < 4; ++reg)
                rssq[wn][wm * 64 + mi * 16 + g * 4 + reg] = ps[mi][reg];
    }
    __syncthreads();
    if (tid < 128) {
        float ssq = rssq[0][tid] + rssq[1][tid] + rssq[2][tid] + rssq[3][tid];
        rinv[tid] = 1.0f / fmaxf(sqrtf(ssq), 1e-12f);
    }
    __syncthreads();

    // write normalized bf16 with [set][b][l] -> [b][set][l] remap
    const int r0  = arow0;                 // multiple of 128
    const int set = r0 >> 14;
    const int bb  = (r0 >> 12) & 3;
    const int l0  = r0 & 4095;
    short* dst = zn + ((size_t)(bb * 2 + set) * 4096 + l0) * 256;
    const int colbase = wn * 64 + (lane & 15);
#pragma unroll
    for (int mi = 0; mi < 4; ++mi)
#pragma unroll
        for (int reg = 0; reg < 4; ++reg) {
            const int rl = wm * 64 + mi * 16 + (lane >> 4) * 4 + reg;
            const float inv = rinv[rl];
#pragma unroll
            for (int ni = 0; ni < 4; ++ni)
                dst[(size_t)rl * 256 + colbase + ni * 16] =
                    f2bf(acc[mi][ni][reg] * inv);
        }
}

// ---------------------------------------------------------------------------
// Symmetric Gram, 256x128 tiles, 512 threads.  grid (64, 32, 4).
// bi = 256-row super-tile (0..31), bj = 128-col tile (0..63).
// (bj>>1)<bi: exit.  ==: diag (rowsums only).  >: rowsums + colsums.
// ---------------------------------------------------------------------------
__global__ __launch_bounds__(512) void gram_kernel(
    const short* __restrict__ zn, float* __restrict__ S)
{
    const int bj = blockIdx.x;
    const int bi = blockIdx.y;
    if ((bj >> 1) < bi) return;
    const bool diag = ((bj >> 1) == bi);
    __shared__ short lsA[16384];   // 256 x 64
    __shared__ short lsB[8192];    // 128 x 64
    const int b = blockIdx.z;
    const short* Z = zn + (size_t)b * (8192 * 256);
    const int arow0 = bi * 256;
    const int brow0 = bj * 128;
    float4v acc[4][4];
#pragma unroll
    for (int mi = 0; mi < 4; ++mi)
#pragma unroll
        for (int ni = 0; ni < 4; ++ni)
            acc[mi][ni] = (float4v){0.f, 0.f, 0.f, 0.f};

    gemm512_core<256, 128, 4>(Z, Z, arow0, brow0, lsA, lsB, acc);

    const int tid  = threadIdx.x;
    const int w    = tid >> 6;
    const int lane = tid & 63;
    const int wm   = w % 4;        // row group of 64
    const int wn   = w / 4;        // col half of 64

    float rs[4][4];
    float cs[4] = {0.f, 0.f, 0.f, 0.f};
#pragma unroll
    for (int mi = 0; mi < 4; ++mi)
#pragma unroll
        for (int reg = 0; reg < 4; ++reg) {
            float s = 0.f;
#pragma unroll
            for (int ni = 0; ni < 4; ++ni) {
                float e = __expf(2.0f * acc[mi][ni][reg]);
                s += e;
                cs[ni] += e;
            }
            rs[mi][reg] = s;
        }
#pragma unroll
    for (int mi = 0; mi < 4; ++mi)
#pragma unroll
        for (int reg = 0; reg < 4; ++reg) {
            float v = rs[mi][reg];
            v += __shfl_xor(v, 1); v += __shfl_xor(v, 2);
            v += __shfl_xor(v, 4); v += __shfl_xor(v, 8);
            rs[mi][reg] = v;
        }
#pragma unroll
    for (int ni = 0; ni < 4; ++ni) {
        float v = cs[ni];
        v += __shfl_xor(v, 16); v += __shfl_xor(v, 32);
        cs[ni] = v;
    }

    // combine wave partials in LDS (reuse lsA; core ended with syncthreads)
    float* rowbuf = (float*)lsA;           // [2 (wn)][256]
    float* colbuf = rowbuf + 512;          // [4 (wm)][128]
    if ((lane & 15) == 0) {
        const int g = lane >> 4;
#pragma unroll
        for (int mi = 0; mi < 4; ++mi)
#pragma unroll
            for (int reg = 0; reg < 4; ++reg)
                rowbuf[wn * 256 + wm * 64 + mi * 16 + g * 4 + reg] = rs[mi][reg];
    }
    if (lane < 16) {
#pragma unroll
        for (int ni = 0; ni < 4; ++ni)
            colbuf[wm * 128 + wn * 64 + ni * 16 + lane] = cs[ni];
    }
    __syncthreads();

    float* Sb = S + (size_t)b * 8192;
    if (tid < 256) {
        atomicAdd(&Sb[arow0 + tid], rowbuf[tid] + rowbuf[256 + tid]);
    } else if (tid < 384 && !diag) {
        const int c = tid - 256;
        atomicAdd(&Sb[brow0 + c],
                  colbuf[c] + colbuf[128 + c] + colbuf[256 + c] + colbuf[384 + c]);
    }
}

// ---------------------------------------------------------------------------
// Final: grid-stride, one wave per row, block-reduce, 1 atomic/block.
// ---------------------------------------------------------------------------
__global__ __launch_bounds__(256) void final_kernel(
    const short* __restrict__ zn, const float* __restrict__ S,
    float* __restrict__ out)
{
    __shared__ float red[4];
    const int tid  = threadIdx.x;
    const int w    = tid >> 6;
    const int lane = tid & 63;
    const float E2 = 7.3890560989306495f;   // exp(1/tau)

    float tacc = 0.f;
    for (int idx = blockIdx.x * 4 + w; idx < 16384; idx += gridDim.x * 4) {
        const int b = idx >> 12;
        const int l = idx & 4095;
        const short4v* z1 = (const short4v*)(zn + ((size_t)(b * 2 + 0) * 4096 + l) * 256);
        const short4v* z2 = (const short4v*)(zn + ((size_t)(b * 2 + 1) * 4096 + l) * 256);
        short4v a = z1[lane];
        short4v c = z2[lane];
        float d = bf2f(a.x) * bf2f(c.x) + bf2f(a.y) * bf2f(c.y)
                + bf2f(a.z) * bf2f(c.z) + bf2f(a.w) * bf2f(c.w);
        d += __shfl_xor(d, 1);  d += __shfl_xor(d, 2);  d += __shfl_xor(d, 4);
        d += __shfl_xor(d, 8);  d += __shfl_xor(d, 16); d += __shfl_xor(d, 32);
        if (lane == 0) {
            float s1 = S[(size_t)b * 8192 + l];
            float s2 = S[(size_t)b * 8192 + 4096 + l];
            tacc += logf(s1 - E2) + logf(s2 - E2) - 4.0f * d;
        }
    }
    if (lane == 0) red[w] = tacc;
    __syncthreads();
    if (tid == 0)
        atomicAdd(out, 0.125f * (red[0] + red[1] + red[2] + red[3]));
}

// ---------------------------------------------------------------------------
// Workspace (bytes), total ~34 MB:
//   [0,        131072)  S     : 4*8192 fp32
//   [131072,   262144)  W1bf
//   [262144,   393216)  W2bf
//   [393216, 17170432)  Xbf / zn (aliased: Xbf dead after proj1; zn written
//                                 by proj2norm which reads only Hbf)
//   [17170432,33947648) Hbf   : 32768*256 bf16
// ---------------------------------------------------------------------------
extern "C" void kernel_launch(void* const* d_in, const int* in_sizes, int n_in,
                              void* d_out, int out_size, void* d_ws, size_t ws_size,
                              hipStream_t stream)
{
    const float* X1 = (const float*)d_in[0];
    const float* X2 = (const float*)d_in[1];
    const float* W1 = (const float*)d_in[2];
    const float* b1 = (const float*)d_in[3];
    const float* W2 = (const float*)d_in[4];
    const float* b2 = (const float*)d_in[5];

    char* ws = (char*)d_ws;
    float* S    = (float*)(ws + 0);
    short* W1bf = (short*)(ws + 131072);
    short* W2bf = (short*)(ws + 262144);
    short* Xbf  = (short*)(ws + 393216);
    short* zn   = (short*)(ws + 393216);
    short* Hbf  = (short*)(ws + 17170432);

    hipMemsetAsync(S, 0, 131072, stream);
    hipMemsetAsync(d_out, 0, sizeof(float), stream);

    convW_kernel<<<128, 256, 0, stream>>>(W1, W2, W1bf, W2bf);
    convX_kernel<<<8192, 256, 0, stream>>>(X1, X2, Xbf);
    proj1_kernel<<<256, 512, 0, stream>>>(Xbf, W1bf, b1, Hbf);
    proj2norm_kernel<<<256, 512, 0, stream>>>(Hbf, W2bf, b2, zn);
    gram_kernel<<<dim3(64, 32, 4), 512, 0, stream>>>(zn, S);
    final_kernel<<<256, 256, 0, stream>>>(zn, S, (float*)d_out);
}

// Round 5
// 332.688 us; speedup vs baseline: 1.9231x; 1.0336x over previous
//
#include <hip/hip_runtime.h>
#include <math.h>

// ---------------------------------------------------------------------------
// Problem: B=4, L=4096, D=P=256, tau=0.5
// out = (1/8) * sum_{b,l} [ log(S1-e^2) + log(S2-e^2) - 4*d[b,l] ]
//   S[b,q] = sum_{m<2L} exp(2 * Zhat[b,q].Zhat[b,m]),  Zhat = [z1n; z2n]
//   d[b,l] = z1n[b,l].z2n[b,l]
// Gram is flash-style: 1 block per (batch, 128-row q-stripe) = 256 blocks,
// A-stripe in registers, B double-buffered in LDS, exp-rowsum + diag-d +
// log(S-e2) all fused in-block.  No S array, no atomic contention, no tail.
// R4 bug fixed: rowsums must be combined ACROSS the 4 wn-waves (each holds a
// 32-col slice) in LDS BEFORE the log — log is nonlinear.
// ---------------------------------------------------------------------------

typedef __attribute__((ext_vector_type(8))) short short8;
typedef __attribute__((ext_vector_type(4))) short short4v;
typedef __attribute__((ext_vector_type(4))) float float4v;

__device__ __forceinline__ short f2bf(float f) {
    unsigned u = __builtin_bit_cast(unsigned, f);
    u += 0x7fffu + ((u >> 16) & 1u);          // RNE
    return (short)(u >> 16);
}

__device__ __forceinline__ void gl_lds16(const short* g, short* l) {
    __builtin_amdgcn_global_load_lds(
        (const __attribute__((address_space(1))) void*)g,
        (__attribute__((address_space(3))) void*)l, 16, 0, 0);
}

// ---------------------------------------------------------------------------
// 512-thread NT-GEMM core (verified R2/R3): C[RAxRB] = A*B^T, K=256.
// ---------------------------------------------------------------------------
template <int RA, int RB, int NWM>
__device__ __forceinline__ void gemm512_core(
    const short* __restrict__ A, const short* __restrict__ B,
    int arow0, int brow0, short* lsA, short* lsB, float4v acc[4][4])
{
    const int tid  = threadIdx.x;
    const int w    = tid >> 6;
    const int lane = tid & 63;
    const int wm   = w % NWM;
    const int wn   = w / NWM;
    constexpr int ACH = RA / 8;

    for (int kt = 0; kt < 4; ++kt) {
        const int kbase = kt * 64;
#pragma unroll
        for (int r = 0; r < 6; ++r) {
            const int c = w * 6 + r;
            if (c < ACH) {
                const int s   = c * 64 + lane;
                const int kc  = s / RA;
                const int row = s % RA;
                gl_lds16(A + (size_t)(arow0 + row) * 256 + kbase + kc * 8,
                         lsA + (size_t)c * 512);
            } else {
                const int s   = (c - ACH) * 64 + lane;
                const int kc  = s / RB;
                const int row = s % RB;
                gl_lds16(B + (size_t)(brow0 + row) * 256 + kbase + kc * 8,
                         lsB + (size_t)(c - ACH) * 512);
            }
        }
        __syncthreads();
#pragma unroll
        for (int ks = 0; ks < 2; ++ks) {
            const int kc = ks * 4 + (lane >> 4);
            short8 af[4], bfv[4];
#pragma unroll
            for (int mi = 0; mi < 4; ++mi)
                af[mi] = *(const short8*)(lsA + ((size_t)kc * RA + wm * 64 + mi * 16 + (lane & 15)) * 8);
#pragma unroll
            for (int ni = 0; ni < 4; ++ni)
                bfv[ni] = *(const short8*)(lsB + ((size_t)kc * RB + wn * 64 + ni * 16 + (lane & 15)) * 8);
#pragma unroll
            for (int mi = 0; mi < 4; ++mi)
#pragma unroll
                for (int ni = 0; ni < 4; ++ni)
                    acc[mi][ni] = __builtin_amdgcn_mfma_f32_16x16x32_bf16(
                        af[mi], bfv[ni], acc[mi][ni], 0, 0, 0);
        }
        __syncthreads();
    }
}

// ---------------------------------------------------------------------------
// fp32 -> bf16 converters
// ---------------------------------------------------------------------------
__global__ __launch_bounds__(256) void convX_kernel(
    const float* __restrict__ X1, const float* __restrict__ X2,
    short* __restrict__ dst)
{
    int i = blockIdx.x * 256 + threadIdx.x;
    const float* src = (i < 1048576) ? X1 : X2;
    int j = i & 1048575;
    float4v v = ((const float4v*)src)[j];
    short4v o;
    o.x = f2bf(v.x); o.y = f2bf(v.y); o.z = f2bf(v.z); o.w = f2bf(v.w);
    ((short4v*)dst)[i] = o;
}

__global__ __launch_bounds__(256) void convW_kernel(
    const float* __restrict__ W1, const float* __restrict__ W2,
    short* __restrict__ d1, short* __restrict__ d2)
{
    int i = blockIdx.x * 256 + threadIdx.x;
    const float* src = (i < 16384) ? W1 : W2;
    short* dst = (i < 16384) ? d1 : d2;
    int j = i & 16383;
    float4v v = ((const float4v*)src)[j];
    short4v o;
    o.x = f2bf(v.x); o.y = f2bf(v.y); o.z = f2bf(v.z); o.w = f2bf(v.w);
    ((short4v*)dst)[j] = o;
}

// ---------------------------------------------------------------------------
// proj1: H = elu(X*W1^T + b1) bf16, 32768x256, grid 256 x 512thr.
// ---------------------------------------------------------------------------
__global__ __launch_bounds__(512) void proj1_kernel(
    const short* __restrict__ Xbf, const short* __restrict__ W1bf,
    const float* __restrict__ b1, short* __restrict__ Hbf)
{
    __shared__ short lsA[8192];
    __shared__ short lsB[16384];
    const int arow0 = blockIdx.x * 128;
    float4v acc[4][4];
#pragma unroll
    for (int mi = 0; mi < 4; ++mi)
#pragma unroll
        for (int ni = 0; ni < 4; ++ni)
            acc[mi][ni] = (float4v){0.f, 0.f, 0.f, 0.f};

    gemm512_core<128, 256, 2>(Xbf, W1bf, arow0, 0, lsA, lsB, acc);

    const int tid  = threadIdx.x;
    const int w    = tid >> 6;
    const int lane = tid & 63;
    const int wm   = w % 2;
    const int wn   = w / 2;
    const int rowbase = arow0 + wm * 64 + (lane >> 4) * 4;
    const int colbase = wn * 64 + (lane & 15);
#pragma unroll
    for (int ni = 0; ni < 4; ++ni) {
        const int col = colbase + ni * 16;
        const float bv = b1[col];
#pragma unroll
        for (int mi = 0; mi < 4; ++mi)
#pragma unroll
            for (int reg = 0; reg < 4; ++reg) {
                const int row = rowbase + mi * 16 + reg;
                float v = acc[mi][ni][reg] + bv;
                v = (v > 0.f) ? v : expm1f(v);
                Hbf[(size_t)row * 256 + col] = f2bf(v);
            }
    }
}

// ---------------------------------------------------------------------------
// proj2 + normalize fused -> zn bf16 in [b][set][l][256] order.
// ---------------------------------------------------------------------------
__global__ __launch_bounds__(512) void proj2norm_kernel(
    const short* __restrict__ Hbf, const short* __restrict__ W2bf,
    const float* __restrict__ b2, short* __restrict__ zn)
{
    __shared__ short lsA[8192];
    __shared__ short lsB[16384];
    __shared__ float rssq[4][128];
    __shared__ float rinv[128];
    const int arow0 = blockIdx.x * 128;
    float4v acc[4][4];
#pragma unroll
    for (int mi = 0; mi < 4; ++mi)
#pragma unroll
        for (int ni = 0; ni < 4; ++ni)
            acc[mi][ni] = (float4v){0.f, 0.f, 0.f, 0.f};

    gemm512_core<128, 256, 2>(Hbf, W2bf, arow0, 0, lsA, lsB, acc);

    const int tid  = threadIdx.x;
    const int w    = tid >> 6;
    const int lane = tid & 63;
    const int wm   = w % 2;
    const int wn   = w / 2;

#pragma unroll
    for (int ni = 0; ni < 4; ++ni) {
        const float bv = b2[wn * 64 + ni * 16 + (lane & 15)];
#pragma unroll
        for (int mi = 0; mi < 4; ++mi)
#pragma unroll
            for (int reg = 0; reg < 4; ++reg)
                acc[mi][ni][reg] += bv;
    }
    float ps[4][4];
#pragma unroll
    for (int mi = 0; mi < 4; ++mi)
#pragma unroll
        for (int reg = 0; reg < 4; ++reg) {
            float s = 0.f;
#pragma unroll
            for (int ni = 0; ni < 4; ++ni) {
                float v = acc[mi][ni][reg];
                s += v * v;
            }
            s += __shfl_xor(s, 1); s += __shfl_xor(s, 2);
            s += __shfl_xor(s, 4); s += __shfl_xor(s, 8);
            ps[mi][reg] = s;
        }
    if ((lane & 15) == 0) {
        const int g = lane >> 4;
#pragma unroll
        for (int mi = 0; mi < 4; ++mi)
#pragma unroll
            for (int reg = 0; reg < 4; ++reg)
                rssq[wn][wm * 64 + mi * 16 + g * 4 + reg] = ps[mi][reg];
    }
    __syncthreads();
    if (tid < 128) {
        float ssq = rssq[0][tid] + rssq[1][tid] + rssq[2][tid] + rssq[3][tid];
        rinv[tid] = 1.0f / fmaxf(sqrtf(ssq), 1e-12f);
    }
    __syncthreads();

    const int r0  = arow0;
    const int set = r0 >> 14;
    const int bb  = (r0 >> 12) & 3;
    const int l0  = r0 & 4095;
    short* dst = zn + ((size_t)(bb * 2 + set) * 4096 + l0) * 256;
    const int colbase = wn * 64 + (lane & 15);
#pragma unroll
    for (int mi = 0; mi < 4; ++mi)
#pragma unroll
        for (int reg = 0; reg < 4; ++reg) {
            const int rl = wm * 64 + mi * 16 + (lane >> 4) * 4 + reg;
            const float inv = rinv[rl];
#pragma unroll
            for (int ni = 0; ni < 4; ++ni)
                dst[(size_t)rl * 256 + colbase + ni * 16] =
                    f2bf(acc[mi][ni][reg] * inv);
        }
}

// ---------------------------------------------------------------------------
// Flash-gram: grid 256 blocks x 512 threads.  Block (batch, stripe) owns
// q-rows [stripe*128, +128) of Zhat[batch]; A-frags in registers; loops the
// 64 j-tiles of 128 keys with double-buffered LDS B.  Fused epilogue:
// per-wave 32-col rowsum partials -> combined across wn in LDS -> log(S-e2);
// raw-diag of the cross tile gives -2*dsum (both orientations sum to -4d);
// one atomicAdd(out) per block.  wave-grid 2m x 4n (64 rows x 32 cols each).
// ---------------------------------------------------------------------------
__global__ __launch_bounds__(512, 2) void gram_flash_kernel(
    const short* __restrict__ zn, float* __restrict__ out)
{
    __shared__ short lsB[2][32768];   // [buf][kseg 0..31][n 0..127][8 bf16]
    __shared__ float smS[4][128];     // [wn][row] rowsum partials
    __shared__ float redl[8];         // per-wave log-sums
    __shared__ float redd[8];         // per-wave dsum

    const int bx     = blockIdx.x;            // 0..255
    const int xcd    = bx & 7;                // XCD-pair swizzle: batch ->
    const int batch  = xcd >> 1;              //   XCDs {2b,2b+1}
    const int stripe = (bx >> 3) * 2 + (xcd & 1);   // 0..63
    const short* Z = zn + (size_t)batch * (8192 * 256);
    const int q0 = stripe * 128;
    const int dj = (stripe < 32) ? (stripe + 32) : (stripe - 32);

    const int tid  = threadIdx.x;
    const int w    = tid >> 6;
    const int lane = tid & 63;
    const int wm   = w & 1;        // m-half (64 rows)
    const int wn   = w >> 1;       // n-quarter (32 cols)
    const int quad = lane >> 4;
    const int l15  = lane & 15;

    // ---- A fragments direct global->regs (once).  A[m=lane&15][k=quad*8+j]
    short8 afr[4][8];
    {
        const short* Ab = Z + (size_t)(q0 + wm * 64) * 256;
#pragma unroll
        for (int mi = 0; mi < 4; ++mi)
#pragma unroll
            for (int kc = 0; kc < 8; ++kc)
                afr[mi][kc] = *(const short8*)(Ab + (size_t)(mi * 16 + l15) * 256
                                               + kc * 32 + quad * 8);
    }

#define STAGE_B(jt, buf)                                                      \
    {                                                                         \
        const short* Bb = Z + (size_t)(jt) * 128 * 256;                       \
        short* dstb = &lsB[buf][0];                                           \
        _Pragma("unroll")                                                     \
        for (int r = 0; r < 8; ++r) {                                         \
            const int c    = w * 8 + r;                                       \
            const int kseg = c >> 1;                                          \
            const int nb   = (c & 1) * 64;                                    \
            gl_lds16(Bb + (size_t)(nb + lane) * 256 + kseg * 8,               \
                     dstb + (size_t)c * 512);                                 \
        }                                                                     \
    }

    STAGE_B(0, 0);

    float rs[4][4];
#pragma unroll
    for (int mi = 0; mi < 4; ++mi)
#pragma unroll
        for (int reg = 0; reg < 4; ++reg)
            rs[mi][reg] = 0.f;
    float dsum = 0.f;

    __syncthreads();

    for (int j = 0; j < 64; ++j) {
        const int buf = j & 1;
        if (j < 63) STAGE_B(j + 1, buf ^ 1);   // full compute window in flight

        float4v acc[4][2];
#pragma unroll
        for (int mi = 0; mi < 4; ++mi) {
            acc[mi][0] = (float4v){0.f, 0.f, 0.f, 0.f};
            acc[mi][1] = (float4v){0.f, 0.f, 0.f, 0.f};
        }
        const short* lb = &lsB[buf][0];
#pragma unroll
        for (int kc = 0; kc < 8; ++kc) {
            const int kseg = kc * 4 + quad;
            short8 bf0 = *(const short8*)(lb + ((size_t)kseg * 128 + wn * 32 + l15) * 8);
            short8 bf1 = *(const short8*)(lb + ((size_t)kseg * 128 + wn * 32 + 16 + l15) * 8);
#pragma unroll
            for (int mi = 0; mi < 4; ++mi) {
                acc[mi][0] = __builtin_amdgcn_mfma_f32_16x16x32_bf16(
                    afr[mi][kc], bf0, acc[mi][0], 0, 0, 0);
                acc[mi][1] = __builtin_amdgcn_mfma_f32_16x16x32_bf16(
                    afr[mi][kc], bf1, acc[mi][1], 0, 0, 0);
            }
        }

        if (j == dj) {   // raw z1.z2 diagonal of the cross tile
#pragma unroll
            for (int mi = 0; mi < 4; ++mi)
#pragma unroll
                for (int ni = 0; ni < 2; ++ni)
#pragma unroll
                    for (int reg = 0; reg < 4; ++reg) {
                        const int row = wm * 64 + mi * 16 + quad * 4 + reg;
                        const int col = wn * 32 + ni * 16 + l15;
                        if (row == col) dsum += acc[mi][ni][reg];
                    }
        }

#pragma unroll
        for (int mi = 0; mi < 4; ++mi)
#pragma unroll
            for (int reg = 0; reg < 4; ++reg)
                rs[mi][reg] += __expf(2.0f * acc[mi][0][reg])
                             + __expf(2.0f * acc[mi][1][reg]);

        __syncthreads();
    }

    // ---- epilogue: combine the 4 wn-wave 32-col partials per row in LDS,
    // THEN take log(S - e2).  (R4 bug: log of per-wave partials.)
    const float E2 = 7.3890560989306495f;   // exp(1/tau) = e^2
#pragma unroll
    for (int mi = 0; mi < 4; ++mi)
#pragma unroll
        for (int reg = 0; reg < 4; ++reg) {
            float v = rs[mi][reg];
            v += __shfl_xor(v, 1); v += __shfl_xor(v, 2);
            v += __shfl_xor(v, 4); v += __shfl_xor(v, 8);
            rs[mi][reg] = v;
        }
    if (l15 == 0) {
#pragma unroll
        for (int mi = 0; mi < 4; ++mi)
#pragma unroll
            for (int reg = 0; reg < 4; ++reg)
                smS[wn][wm * 64 + mi * 16 + quad * 4 + reg] = rs[mi][reg];
    }
    // dsum: full-wave reduce -> redd[w]
    {
        float dv = dsum;
        dv += __shfl_xor(dv, 1);  dv += __shfl_xor(dv, 2);
        dv += __shfl_xor(dv, 4);  dv += __shfl_xor(dv, 8);
        dv += __shfl_xor(dv, 16); dv += __shfl_xor(dv, 32);
        if (lane == 0) redd[w] = dv;
    }
    __syncthreads();

    float local = 0.f;
    if (tid < 128)
        local = logf(smS[0][tid] + smS[1][tid] + smS[2][tid] + smS[3][tid] - E2);
    local += __shfl_xor(local, 1);  local += __shfl_xor(local, 2);
    local += __shfl_xor(local, 4);  local += __shfl_xor(local, 8);
    local += __shfl_xor(local, 16); local += __shfl_xor(local, 32);
    if (lane == 0) redl[w] = local;
    __syncthreads();
    if (tid == 0) {
        float t = redl[0] + redl[1] + redl[2] + redl[3]
                + redl[4] + redl[5] + redl[6] + redl[7]
                - 2.0f * (redd[0] + redd[1] + redd[2] + redd[3]
                        + redd[4] + redd[5] + redd[6] + redd[7]);
        atomicAdd(out, 0.125f * t);
    }
#undef STAGE_B
}

// ---------------------------------------------------------------------------
// Workspace (bytes), total ~33.8 MB:
//   [0,       131072)  W1bf
//   [131072,  262144)  W2bf
//   [262144,17039360)  Xbf / zn (aliased; Xbf dead after proj1)
//   [17039360,33816576) Hbf
// ---------------------------------------------------------------------------
extern "C" void kernel_launch(void* const* d_in, const int* in_sizes, int n_in,
                              void* d_out, int out_size, void* d_ws, size_t ws_size,
                              hipStream_t stream)
{
    const float* X1 = (const float*)d_in[0];
    const float* X2 = (const float*)d_in[1];
    const float* W1 = (const float*)d_in[2];
    const float* b1 = (const float*)d_in[3];
    const float* W2 = (const float*)d_in[4];
    const float* b2 = (const float*)d_in[5];

    char* ws = (char*)d_ws;
    short* W1bf = (short*)(ws + 0);
    short* W2bf = (short*)(ws + 131072);
    short* Xbf  = (short*)(ws + 262144);
    short* zn   = (short*)(ws + 262144);
    short* Hbf  = (short*)(ws + 17039360);

    hipMemsetAsync(d_out, 0, sizeof(float), stream);

    convW_kernel<<<128, 256, 0, stream>>>(W1, W2, W1bf, W2bf);
    convX_kernel<<<8192, 256, 0, stream>>>(X1, X2, Xbf);
    proj1_kernel<<<256, 512, 0, stream>>>(Xbf, W1bf, b1, Hbf);
    proj2norm_kernel<<<256, 512, 0, stream>>>(Hbf, W2bf, b2, zn);
    gram_flash_kernel<<<256, 512, 0, stream>>>(zn, (float*)d_out);
}